// Round 1
// baseline (45.462 us; speedup 1.0000x reference)
//
#include <hip/hip_runtime.h>
#include <math.h>

#define TT 32768
#define DD 1024

// One wave (64 lanes) per token: 16 elements/lane as 4x float4.
// fp64 range reduction -> hardware v_sin/v_cos (revolution input).
__global__ __launch_bounds__(256) void genuine_embedding_kernel(
    const float* __restrict__ tokv,
    const float* __restrict__ posv,
    const float* __restrict__ reso,
    const float* __restrict__ scal,
    const float* __restrict__ shft,
    const float* __restrict__ enrm,
    float* __restrict__ out)
{
    const int wave = threadIdx.x >> 6;
    const int lane = threadIdx.x & 63;
    const int t = (blockIdx.x << 2) + wave;   // 4 tokens per block

    // angle base: bit-exact with reference fp32 (add, then per-elem mul)
    const float a  = tokv[t] + posv[t];
    const float en = enrm[0];

    const float4* __restrict__ rp = reinterpret_cast<const float4*>(reso) + ((size_t)t << 8);
    const float4* __restrict__ sp = reinterpret_cast<const float4*>(scal);
    const float4* __restrict__ hp = reinterpret_cast<const float4*>(shft);
    float4* __restrict__ op       = reinterpret_cast<float4*>(out)  + ((size_t)t << 8);

    const double INV2PI = 0.15915494309189534943238462643383;  // 1/(2*pi), fp64

    float4 comp[4];
    float sumsq = 0.0f;

#pragma unroll
    for (int j = 0; j < 4; ++j) {
        const int idx = lane + (j << 6);      // float4 index within the 256-float4 row
        float4 r4 = rp[idx];
        float4 sc = sp[idx];
        float4 sh = hp[idx];
        float rr[4] = {r4.x, r4.y, r4.z, r4.w};
        float ss[4] = {sc.x, sc.y, sc.z, sc.w};
        float hh[4] = {sh.x, sh.y, sh.z, sh.w};
        float cv[4];
#pragma unroll
        for (int e = 0; e < 4; ++e) {
            float angle = rr[e] * a;                  // matches ref fp32 exactly
            // fp64 range reduction to revolutions in [0,1): angle >= 0 here
            double v = (double)angle * INV2PI;
            v = v - floor(v);
            float vf = (float)v;
            float s = __builtin_amdgcn_sinf(vf);      // sin(2*pi*vf)
            float c = __builtin_amdgcn_cosf(vf);      // cos(2*pi*vf)
            float cm = c * (1.0f + s) + s * s;
            cm = cm * ss[e] + hh[e];
            cv[e] = cm;
            sumsq += cm * cm;
        }
        comp[j] = make_float4(cv[0], cv[1], cv[2], cv[3]);
    }

    // wave-wide sum of squares (64 lanes), butterfly
#pragma unroll
    for (int o = 32; o > 0; o >>= 1)
        sumsq += __shfl_xor(sumsq, o, 64);

    const float nrm = sqrtf(sumsq);
    const float inv = (nrm > 0.0f) ? (en / nrm) : 1.0f;

#pragma unroll
    for (int j = 0; j < 4; ++j) {
        const int idx = lane + (j << 6);
        float4 c4 = comp[j];
        c4.x *= inv; c4.y *= inv; c4.z *= inv; c4.w *= inv;
        op[idx] = c4;
    }
}

extern "C" void kernel_launch(void* const* d_in, const int* in_sizes, int n_in,
                              void* d_out, int out_size, void* d_ws, size_t ws_size,
                              hipStream_t stream) {
    const float* tokv = (const float*)d_in[0];
    const float* posv = (const float*)d_in[1];
    const float* reso = (const float*)d_in[2];
    const float* scal = (const float*)d_in[3];
    const float* shft = (const float*)d_in[4];
    const float* enrm = (const float*)d_in[5];
    float* out = (float*)d_out;

    genuine_embedding_kernel<<<TT / 4, 256, 0, stream>>>(
        tokv, posv, reso, scal, shft, enrm, out);
}